// Round 1
// baseline (32.713 us; speedup 1.0000x reference)
//
#include <hip/hip_runtime.h>
#include <math.h>

#define G 128
#define NCELLS (G*G)            // 16384
#define RAD 20
#define NS 41                   // 2R+1
#define NTAPS (NS*NS)           // 1681
#define NB_FULL 1850.0f         // 1 + (2R+3)^2 slots in the mean
#define NTAIL 168.0f            // (2R+3)^2 - (2R+1)^2
#define WROWPAD 44
#define WSZ (NS*WROWPAD)        // 1804 floats per rule
#define NRULES 4

// ws layout (float offsets)
#define WOFF_W     0                          // 4 * 1804 padded stencils
#define WOFF_TAIL  (NRULES*WSZ)               // 7216: 4 tail scalars
#define WOFF_POT   (WOFF_TAIL + 4)            // 7220: 4 * N potentials
#define WOFF_PLANE (WOFF_POT + NRULES*NCELLS) // 72756: 3 * N channel planes

__device__ __forceinline__ float kernel_w(float d, float r_k,
                                          float rk0, float rk1, float rk2,
                                          float b0, float b1, float b2,
                                          float w0, float w1, float w2) {
    float em = 1.f / (1.f + __expf(0.f) * expf((d - 1.f) * 10.f));
    float dd = d / r_k;
    float q0 = (dd - rk0) / w0;
    float q1 = (dd - rk1) / w1;
    float q2 = (dd - rk2) / w2;
    float ssum = b0 * expf(-0.5f * q0 * q0)
               + b1 * expf(-0.5f * q1 * q1)
               + b2 * expf(-0.5f * q2 * q2);
    return em * ssum;
}

// blocks 0..3: compute normalized stencil for rule k (padded rows of 44)
// blocks 4..67: deinterleave x[N][3] -> planes[3][N]
__global__ __launch_bounds__(256)
void lenia_prep(const float* __restrict__ x,
                const float* __restrict__ rr,
                const float* __restrict__ rkv,
                const float* __restrict__ bv,
                const float* __restrict__ wv,
                float* __restrict__ ws) {
    const int bid = blockIdx.x;
    const int t = threadIdx.x;

    if (bid >= NRULES) {
        int n = (bid - NRULES) * 256 + t;
        float v0 = x[n*3 + 0];
        float v1 = x[n*3 + 1];
        float v2 = x[n*3 + 2];
        ws[WOFF_PLANE + 0*NCELLS + n] = v0;
        ws[WOFF_PLANE + 1*NCELLS + n] = v1;
        ws[WOFF_PLANE + 2*NCELLS + n] = v2;
        return;
    }

    __shared__ float red[256];
    const int k = bid;
    const float r_k = rr[k];
    const float rk0 = rkv[k*3+0], rk1 = rkv[k*3+1], rk2 = rkv[k*3+2];
    const float b0  = bv[k*3+0],  b1  = bv[k*3+1],  b2  = bv[k*3+2];
    const float w0  = wv[k*3+0],  w1  = wv[k*3+1],  w2  = wv[k*3+2];

    float vals[7];
    float lsum = 0.f;
    #pragma unroll
    for (int q = 0; q < 7; ++q) {
        int sidx = t + q * 256;
        vals[q] = 0.f;
        if (sidx < NTAPS) {
            int si = sidx / NS - RAD;
            int sj = sidx % NS - RAD;
            float d = sqrtf((float)(si*si + sj*sj)) / (float)RAD;
            float wk = kernel_w(d, r_k, rk0, rk1, rk2, b0, b1, b2, w0, w1, w2);
            vals[q] = wk;
            lsum += wk;
        }
    }
    red[t] = lsum;
    __syncthreads();
    for (int off = 128; off > 0; off >>= 1) {
        if (t < off) red[t] += red[t + off];
        __syncthreads();
    }
    const float wself = kernel_w(0.f, r_k, rk0, rk1, rk2, b0, b1, b2, w0, w1, w2);
    const float dtail = sqrtf(8192.f) / (float)RAD;   // |pos[0]-pos[center]| / R
    const float wtail = kernel_w(dtail, r_k, rk0, rk1, rk2, b0, b1, b2, w0, w1, w2);
    const float S = red[0] + wself + NTAIL * wtail;
    const float inv = 1.f / (S * NB_FULL);

    #pragma unroll
    for (int q = 0; q < 7; ++q) {
        int sidx = t + q * 256;
        if (sidx < NTAPS) {
            float v = vals[q] * inv;
            if (sidx == (RAD * NS + RAD)) v += wself * inv;  // fold self slot into (0,0)
            ws[WOFF_W + k*WSZ + (sidx / NS) * WROWPAD + (sidx % NS)] = v;
        }
    }
    // zero the pad columns 41..43
    for (int idx = t; idx < NS * (WROWPAD - NS); idx += 256) {
        int row = idx / (WROWPAD - NS);
        int col = NS + idx % (WROWPAD - NS);
        ws[WOFF_W + k*WSZ + row * WROWPAD + col] = 0.f;
    }
    if (t == 0) ws[WOFF_TAIL + k] = NTAIL * wtail * inv;
}

// 256 blocks: (64 two-row tiles) x (4 rules). 128 threads, 2 adjacent cells each.
__global__ __launch_bounds__(128)
void lenia_conv(const int* __restrict__ c0, float* __restrict__ ws) {
    __shared__ __align__(16) float sh[42*168 + WSZ];
    float* xt = sh;             // [42][168] halo'd channel tile
    float* wl = sh + 42*168;    // [41][44] stencil

    const int bid = blockIdx.x;
    const int tile = bid >> 2;
    const int k = bid & 3;
    const int i0 = tile * 2;
    const int t = threadIdx.x;
    const int ck = c0[k];       // wave-uniform
    const float* xp = ws + WOFF_PLANE + ck * NCELLS;

    // stage stencil
    for (int idx = t; idx < WSZ; idx += 128) wl[idx] = ws[WOFF_W + k*WSZ + idx];
    // stage interior columns (global cols 0..127 -> lds cols 20..147) as float4
    for (int idx = t; idx < 42*32; idx += 128) {
        int rrow = idx >> 5, q = idx & 31;
        int grow = (i0 - RAD + rrow) & (G - 1);
        *(float4*)&xt[rrow*168 + 20 + q*4] = *(const float4*)&xp[grow*G + q*4];
    }
    // stage wrap halo columns (lds cols 0..19 and 148..167)
    for (int idx = t; idx < 42*40; idx += 128) {
        int rrow = idx / 40, h = idx % 40;
        int cc = (h < 20) ? h : (h + 128);
        int grow = (i0 - RAD + rrow) & (G - 1);
        int gcol = (cc - 20) & (G - 1);
        xt[rrow*168 + cc] = xp[grow*G + gcol];
    }
    __syncthreads();

    const int row = t >> 6;              // 0..1
    const int colbase = (t & 63) * 2;    // even column
    float a0 = 0.f, a1 = 0.f, a2 = 0.f, a3 = 0.f;

    for (int si = 0; si < NS; ++si) {
        const float* rp = &xt[(row + si)*168 + colbase];
        float wwin[42];
        #pragma unroll
        for (int q = 0; q < 21; ++q) {
            float2 v = *(const float2*)&rp[2*q];
            wwin[2*q] = v.x; wwin[2*q+1] = v.y;
        }
        float wrow[44];
        #pragma unroll
        for (int q = 0; q < 11; ++q) {
            float4 v = *(const float4*)&wl[si*WROWPAD + 4*q];
            wrow[4*q] = v.x; wrow[4*q+1] = v.y; wrow[4*q+2] = v.z; wrow[4*q+3] = v.w;
        }
        #pragma unroll
        for (int s2 = 0; s2 < 40; s2 += 2) {
            a0 = fmaf(wrow[s2],   wwin[s2],   a0);
            a1 = fmaf(wrow[s2],   wwin[s2+1], a1);
            a2 = fmaf(wrow[s2+1], wwin[s2+1], a2);
            a3 = fmaf(wrow[s2+1], wwin[s2+2], a3);
        }
        a0 = fmaf(wrow[40], wwin[40], a0);
        a1 = fmaf(wrow[40], wwin[41], a1);
    }

    const float tail = ws[WOFF_TAIL + k] * xp[0];
    float p0 = a0 + a2 + tail;
    float p1 = a1 + a3 + tail;
    int cell = (i0 + row) * G + colbase;
    ws[WOFF_POT + k*NCELLS + cell]     = p0;
    ws[WOFF_POT + k*NCELLS + cell + 1] = p1;
}

// 64 blocks x 256: growth, delta, clip, plus pos pass-through.
__global__ __launch_bounds__(256)
void lenia_update(const float* __restrict__ pos,
                  const float* __restrict__ x,
                  const int* __restrict__ c1,
                  const float* __restrict__ hv,
                  const float* __restrict__ mv,
                  const float* __restrict__ sv,
                  const float* __restrict__ ws,
                  float* __restrict__ out) {
    int n = blockIdx.x * 256 + threadIdx.x;
    out[2*n]     = pos[2*n];
    out[2*n + 1] = pos[2*n + 1];

    float xv0 = x[n*3 + 0], xv1 = x[n*3 + 1], xv2 = x[n*3 + 2];
    float d0 = 0.f, d1 = 0.f, d2 = 0.f;
    #pragma unroll
    for (int k = 0; k < NRULES; ++k) {
        float pot = ws[WOFF_POT + k*NCELLS + n];
        float mk = mv[k], sk = sv[k];
        float u = pot - mk;
        float field = expf(-u*u / (2.f * sk * sk) - 0.001f) * 2.f - 1.f;
        float add = hv[k] * field;
        int c = c1[k];   // wave-uniform
        if (c == 0) d0 += add; else if (c == 1) d1 += add; else d2 += add;
    }
    float* ox = out + 2*NCELLS;
    ox[n*3 + 0] = fminf(fmaxf(xv0 + d0 * 0.1f, 0.f), 1.f);
    ox[n*3 + 1] = fminf(fmaxf(xv1 + d1 * 0.1f, 0.f), 1.f);
    ox[n*3 + 2] = fminf(fmaxf(xv2 + d2 * 0.1f, 0.f), 1.f);
}

extern "C" void kernel_launch(void* const* d_in, const int* in_sizes, int n_in,
                              void* d_out, int out_size, void* d_ws, size_t ws_size,
                              hipStream_t stream) {
    const float* pos = (const float*)d_in[0];
    const float* x   = (const float*)d_in[1];
    const int*   c0  = (const int*)  d_in[2];
    const int*   c1  = (const int*)  d_in[3];
    const float* r   = (const float*)d_in[4];
    const float* rk  = (const float*)d_in[5];
    const float* b   = (const float*)d_in[6];
    const float* w   = (const float*)d_in[7];
    const float* h   = (const float*)d_in[8];
    const float* m   = (const float*)d_in[9];
    const float* s   = (const float*)d_in[10];
    float* out = (float*)d_out;
    float* ws  = (float*)d_ws;

    lenia_prep<<<NRULES + NCELLS/256, 256, 0, stream>>>(x, r, rk, b, w, ws);
    lenia_conv<<<(G/2) * NRULES, 128, 0, stream>>>(c0, ws);
    lenia_update<<<NCELLS/256, 256, 0, stream>>>(pos, x, c1, h, m, s, ws, out);
}

// Round 2
// 24.707 us; speedup vs baseline: 1.3240x; 1.3240x over previous
//
#include <hip/hip_runtime.h>
#include <math.h>

#define G 128
#define NCELLS (G*G)            // 16384
#define RAD 20
#define NS 41                   // 2R+1
#define NTAPS (NS*NS)           // 1681
#define NB_FULL 1850.0f         // 1 + (2R+3)^2 slots in the mean
#define NTAIL 168.0f            // (2R+3)^2 - (2R+1)^2
#define WROWPAD 44
#define WSZ (NS*WROWPAD)        // 1804 floats per rule
#define NRULES 4
#define NQ 4                    // tap-split factor (stencil-row quarters)

// ws layout (float offsets)
#define WOFF_W     0                              // 4 * 1804 padded stencils
#define WOFF_TAIL  (NRULES*WSZ)                   // 7216: 4 tail scalars
#define WOFF_POT   (WOFF_TAIL + 4)                // 7220: 16 * N partial potentials
#define WOFF_PLANE (WOFF_POT + NRULES*NQ*NCELLS)  // 3 * N channel planes

__device__ __forceinline__ float kernel_w(float d, float r_k,
                                          float rk0, float rk1, float rk2,
                                          float b0, float b1, float b2,
                                          float w0, float w1, float w2) {
    float em = 1.f / (1.f + expf((d - 1.f) * 10.f));
    float dd = d / r_k;
    float q0 = (dd - rk0) / w0;
    float q1 = (dd - rk1) / w1;
    float q2 = (dd - rk2) / w2;
    float ssum = b0 * expf(-0.5f * q0 * q0)
               + b1 * expf(-0.5f * q1 * q1)
               + b2 * expf(-0.5f * q2 * q2);
    return em * ssum;
}

// blocks 0..3: compute normalized stencil for rule k (padded rows of 44)
// blocks 4..67: deinterleave x[N][3] -> planes[3][N]
__global__ __launch_bounds__(256)
void lenia_prep(const float* __restrict__ x,
                const float* __restrict__ rr,
                const float* __restrict__ rkv,
                const float* __restrict__ bv,
                const float* __restrict__ wv,
                float* __restrict__ ws) {
    const int bid = blockIdx.x;
    const int t = threadIdx.x;

    if (bid >= NRULES) {
        int n = (bid - NRULES) * 256 + t;
        float v0 = x[n*3 + 0];
        float v1 = x[n*3 + 1];
        float v2 = x[n*3 + 2];
        ws[WOFF_PLANE + 0*NCELLS + n] = v0;
        ws[WOFF_PLANE + 1*NCELLS + n] = v1;
        ws[WOFF_PLANE + 2*NCELLS + n] = v2;
        return;
    }

    __shared__ float red[256];
    const int k = bid;
    const float r_k = rr[k];
    const float rk0 = rkv[k*3+0], rk1 = rkv[k*3+1], rk2 = rkv[k*3+2];
    const float b0  = bv[k*3+0],  b1  = bv[k*3+1],  b2  = bv[k*3+2];
    const float w0  = wv[k*3+0],  w1  = wv[k*3+1],  w2  = wv[k*3+2];

    float vals[7];
    float lsum = 0.f;
    #pragma unroll
    for (int q = 0; q < 7; ++q) {
        int sidx = t + q * 256;
        vals[q] = 0.f;
        if (sidx < NTAPS) {
            int si = sidx / NS - RAD;
            int sj = sidx % NS - RAD;
            float d = sqrtf((float)(si*si + sj*sj)) / (float)RAD;
            float wk = kernel_w(d, r_k, rk0, rk1, rk2, b0, b1, b2, w0, w1, w2);
            vals[q] = wk;
            lsum += wk;
        }
    }
    red[t] = lsum;
    __syncthreads();
    for (int off = 128; off > 0; off >>= 1) {
        if (t < off) red[t] += red[t + off];
        __syncthreads();
    }
    const float wself = kernel_w(0.f, r_k, rk0, rk1, rk2, b0, b1, b2, w0, w1, w2);
    const float dtail = sqrtf(8192.f) / (float)RAD;   // |pos[0]-pos[center]| / R
    const float wtail = kernel_w(dtail, r_k, rk0, rk1, rk2, b0, b1, b2, w0, w1, w2);
    const float S = red[0] + wself + NTAIL * wtail;
    const float inv = 1.f / (S * NB_FULL);

    #pragma unroll
    for (int q = 0; q < 7; ++q) {
        int sidx = t + q * 256;
        if (sidx < NTAPS) {
            float v = vals[q] * inv;
            if (sidx == (RAD * NS + RAD)) v += wself * inv;  // fold self slot into (0,0)
            ws[WOFF_W + k*WSZ + (sidx / NS) * WROWPAD + (sidx % NS)] = v;
        }
    }
    // zero the pad columns 41..43
    for (int idx = t; idx < NS * (WROWPAD - NS); idx += 256) {
        int row = idx / (WROWPAD - NS);
        int col = NS + idx % (WROWPAD - NS);
        ws[WOFF_W + k*WSZ + row * WROWPAD + col] = 0.f;
    }
    if (t == 0) ws[WOFF_TAIL + k] = NTAIL * wtail * inv;
}

// 512 blocks: (32 four-row tiles) x (4 rules) x (4 stencil-row quarters).
// 256 threads: row = t>>6 (0..3), 2 adjacent cells per thread.
// Stencil rows are read with block-uniform addresses straight from global
// (SMEM/s_load path) so the LDS pipe only carries the per-lane window reads.
__global__ __launch_bounds__(256)
void lenia_conv(const int* __restrict__ c0, float* __restrict__ ws) {
    __shared__ __align__(16) float xt[14*168];   // up to 14 halo'd rows

    const int bid  = blockIdx.x;
    const int q    = bid & 3;
    const int k    = (bid >> 2) & 3;
    const int tile = bid >> 4;                   // 0..31
    const int i0   = tile * 4;
    const int t    = threadIdx.x;

    const int si0 = (q == 0) ? 0 : (q * 10 + 1); // quarters: 11,10,10,10 rows
    const int nsi = (q == 0) ? 11 : 10;
    const int r0  = i0 - RAD + si0;              // first x-row needed
    const int NR  = nsi + 3;                     // rows to stage (<=14)

    const int ck = c0[k];                        // wave-uniform
    const float* xp = ws + WOFF_PLANE + ck * NCELLS;
    const float* wgl = ws + WOFF_W + k * WSZ;

    // stage interior columns (global cols 0..127 -> lds cols 20..147) as float4
    for (int idx = t; idx < NR*32; idx += 256) {
        int rrow = idx >> 5, qq = idx & 31;
        int grow = (r0 + rrow) & (G - 1);
        *(float4*)&xt[rrow*168 + 20 + qq*4] = *(const float4*)&xp[grow*G + qq*4];
    }
    // stage wrap halo columns (lds cols 0..19 and 148..167)
    for (int idx = t; idx < NR*40; idx += 256) {
        int rrow = idx / 40, h = idx % 40;
        int cc = (h < 20) ? h : (h + 128);
        int grow = (r0 + rrow) & (G - 1);
        int gcol = (cc - 20) & (G - 1);
        xt[rrow*168 + cc] = xp[grow*G + gcol];
    }
    __syncthreads();

    const int row = t >> 6;              // 0..3
    const int colbase = (t & 63) * 2;    // even column
    float a0 = 0.f, a1 = 0.f, a2 = 0.f, a3 = 0.f;

    for (int ii = 0; ii < nsi; ++ii) {
        const float* rp = &xt[(row + ii)*168 + colbase];
        float wwin[42];
        #pragma unroll
        for (int u = 0; u < 21; ++u) {
            float2 v = *(const float2*)&rp[2*u];
            wwin[2*u] = v.x; wwin[2*u+1] = v.y;
        }
        const float* wr = wgl + (si0 + ii) * WROWPAD;   // block-uniform address
        float wrow[44];
        #pragma unroll
        for (int u = 0; u < 11; ++u) {
            float4 v = *(const float4*)&wr[4*u];
            wrow[4*u] = v.x; wrow[4*u+1] = v.y; wrow[4*u+2] = v.z; wrow[4*u+3] = v.w;
        }
        #pragma unroll
        for (int s2 = 0; s2 < 40; s2 += 2) {
            a0 = fmaf(wrow[s2],   wwin[s2],   a0);
            a1 = fmaf(wrow[s2],   wwin[s2+1], a1);
            a2 = fmaf(wrow[s2+1], wwin[s2+1], a2);
            a3 = fmaf(wrow[s2+1], wwin[s2+2], a3);
        }
        a0 = fmaf(wrow[40], wwin[40], a0);
        a1 = fmaf(wrow[40], wwin[41], a1);
    }

    int cell = (i0 + row) * G + colbase;
    float* pp = ws + WOFF_POT + (k * NQ + q) * NCELLS;
    pp[cell]     = a0 + a2;
    pp[cell + 1] = a1 + a3;
}

// 64 blocks x 256: sum partials, growth, delta, clip, plus pos pass-through.
__global__ __launch_bounds__(256)
void lenia_update(const float* __restrict__ pos,
                  const float* __restrict__ x,
                  const int* __restrict__ c0,
                  const int* __restrict__ c1,
                  const float* __restrict__ hv,
                  const float* __restrict__ mv,
                  const float* __restrict__ sv,
                  const float* __restrict__ ws,
                  float* __restrict__ out) {
    int n = blockIdx.x * 256 + threadIdx.x;
    out[2*n]     = pos[2*n];
    out[2*n + 1] = pos[2*n + 1];

    float xv0 = x[n*3 + 0], xv1 = x[n*3 + 1], xv2 = x[n*3 + 2];
    float d0 = 0.f, d1 = 0.f, d2 = 0.f;
    #pragma unroll
    for (int k = 0; k < NRULES; ++k) {
        float tail = ws[WOFF_TAIL + k] * x[c0[k]];   // tail slots all point at cell 0
        float pot = tail;
        #pragma unroll
        for (int qq = 0; qq < NQ; ++qq)
            pot += ws[WOFF_POT + (k * NQ + qq) * NCELLS + n];
        float mk = mv[k], sk = sv[k];
        float u = pot - mk;
        float field = expf(-u*u / (2.f * sk * sk) - 0.001f) * 2.f - 1.f;
        float add = hv[k] * field;
        int c = c1[k];   // wave-uniform
        if (c == 0) d0 += add; else if (c == 1) d1 += add; else d2 += add;
    }
    float* ox = out + 2*NCELLS;
    ox[n*3 + 0] = fminf(fmaxf(xv0 + d0 * 0.1f, 0.f), 1.f);
    ox[n*3 + 1] = fminf(fmaxf(xv1 + d1 * 0.1f, 0.f), 1.f);
    ox[n*3 + 2] = fminf(fmaxf(xv2 + d2 * 0.1f, 0.f), 1.f);
}

extern "C" void kernel_launch(void* const* d_in, const int* in_sizes, int n_in,
                              void* d_out, int out_size, void* d_ws, size_t ws_size,
                              hipStream_t stream) {
    const float* pos = (const float*)d_in[0];
    const float* x   = (const float*)d_in[1];
    const int*   c0  = (const int*)  d_in[2];
    const int*   c1  = (const int*)  d_in[3];
    const float* r   = (const float*)d_in[4];
    const float* rk  = (const float*)d_in[5];
    const float* b   = (const float*)d_in[6];
    const float* w   = (const float*)d_in[7];
    const float* h   = (const float*)d_in[8];
    const float* m   = (const float*)d_in[9];
    const float* s   = (const float*)d_in[10];
    float* out = (float*)d_out;
    float* ws  = (float*)d_ws;

    lenia_prep<<<NRULES + NCELLS/256, 256, 0, stream>>>(x, r, rk, b, w, ws);
    lenia_conv<<<(G/4) * NRULES * NQ, 256, 0, stream>>>(c0, ws);
    lenia_update<<<NCELLS/256, 256, 0, stream>>>(pos, x, c0, c1, h, m, s, ws, out);
}